// Round 8
// baseline (144.365 us; speedup 1.0000x reference)
//
#include <hip/hip_runtime.h>
#include <hip/hip_bf16.h>

// Problem constants
#define BB   16384
#define DD   128
#define HH   4
#define EE   8
#define NN   (BB*HH)   // 65536
#define OD   32
#define PT   136       // LDS row pitch in bf16 elems (128 + 8)
#define GNB  256       // k1_gate grid
#define KPE  128       // k2b persistent blocks per expert

typedef __attribute__((ext_vector_type(8))) short short8;
typedef __attribute__((ext_vector_type(4))) short short4v;
typedef __attribute__((ext_vector_type(4))) float f32x4;

// RNE float -> bf16 bits
static __device__ __forceinline__ short f2bf(float v) {
    unsigned int u = __builtin_bit_cast(unsigned int, v);
    u = (u + 0x7FFFu + ((u >> 16) & 1u)) >> 16;
    return (short)u;
}

// ---------------------------------------------------------------------------
// PREP (fused): weights -> bf16 in MFMA fragment order (coalesced A-loads),
// gate collapse precompute, out[] = bout init, cursors/doneCnt = 0.
// Fragment order: 16(m)x32(k) A-tile, lane=(quad<<4)|l16 holds m=l16,
// k=quad*8+j, 8 contiguous shorts/lane: flat = ((tile*4+ks)*64+lane)*8+j.
// ---------------------------------------------------------------------------
__global__ __launch_bounds__(256) void prep(
    const float* __restrict__ Wq, const float* __restrict__ Wk, const float* __restrict__ Wg,
    const float* __restrict__ bk, const float* __restrict__ W1, const float* __restrict__ W2,
    const float* __restrict__ bout,
    short* __restrict__ WqF, short* __restrict__ W1F, short* __restrict__ W2F,
    float* __restrict__ Wkg, float* __restrict__ bkg, float* __restrict__ out,
    int* __restrict__ cursors, int* __restrict__ doneCnt)
{
    int idx = blockIdx.x * 256 + threadIdx.x;
    if (idx < 65536) {
        int j = idx & 7, lane = (idx >> 3) & 63, ks = (idx >> 9) & 3, ct = idx >> 11;
        int l16 = lane & 15, quad = lane >> 4;
        int c = ct * 16 + l16, k = ks * 32 + quad * 8 + j;
        WqF[idx] = f2bf(Wq[k * 512 + c]);
    } else if (idx < 196608) {
        int r = idx - 65536;
        int j = r & 7, lane = (r >> 3) & 63, ks = (r >> 9) & 3, mt = (r >> 11) & 7, e = r >> 14;
        int l16 = lane & 15, quad = lane >> 4;
        int m = mt * 16 + l16, k = ks * 32 + quad * 8 + j;
        W1F[r] = f2bf(W1[e * 16384 + k * 128 + m]);
    } else if (idx < 229376) {
        int r = idx - 196608;
        int j = r & 7, lane = (r >> 3) & 63, ks = (r >> 9) & 3, mt = (r >> 11) & 1, e = r >> 12;
        int l16 = lane & 15, quad = lane >> 4;
        int m = mt * 16 + l16, k = ks * 32 + quad * 8 + j;
        W2F[r] = f2bf(W2[e * 4096 + k * 32 + m]);
    } else if (idx < 233472) {
        int r = idx - 229376;
        int k = r >> 5, col = r & 31, hh = col >> 3, e = col & 7;
        float s = 0.f;
        for (int d = 0; d < 128; ++d) s += Wk[k * 512 + hh * 128 + d] * Wg[d * 8 + e];
        Wkg[k * 32 + col] = s;
    } else if (idx < 233504) {
        int r = idx - 233472;
        int hh = r >> 3, e = r & 7;
        float s = 0.f;
        for (int d = 0; d < 128; ++d) s += bk[hh * 128 + d] * Wg[d * 8 + e];
        bkg[r] = s;
    } else if (idx < 249888) {
        out[idx - 233504] = bout[0];
    } else if (idx < 249896) {
        cursors[idx - 249888] = 0;
    } else if (idx == 249896) {
        *doneCnt = 0;
    }
}

// ---------------------------------------------------------------------------
// K1q: tok = bf16(x @ Wq + bq) via MFMA, D[c][b] (swapped operands).
//      A-frags from fragment-ordered WqF (coalesced 16B/lane loads).
// ---------------------------------------------------------------------------
__global__ __launch_bounds__(256) void k1q_tok(
    const float* __restrict__ x, const short* __restrict__ WqF, const float* __restrict__ bq,
    short* __restrict__ tokb)
{
    __shared__ short xL[32 * PT];
    const int t  = threadIdx.x;
    const int b0 = blockIdx.x * 32;

    {
        int slot = t >> 3, seg = t & 7;
        const float4* src = (const float4*)(x + (size_t)(b0 + slot) * 128 + seg * 16);
        float4 v0 = src[0], v1 = src[1], v2 = src[2], v3 = src[3];
        short8 a, b;
        a[0]=f2bf(v0.x); a[1]=f2bf(v0.y); a[2]=f2bf(v0.z); a[3]=f2bf(v0.w);
        a[4]=f2bf(v1.x); a[5]=f2bf(v1.y); a[6]=f2bf(v1.z); a[7]=f2bf(v1.w);
        b[0]=f2bf(v2.x); b[1]=f2bf(v2.y); b[2]=f2bf(v2.z); b[3]=f2bf(v2.w);
        b[4]=f2bf(v3.x); b[5]=f2bf(v3.y); b[6]=f2bf(v3.z); b[7]=f2bf(v3.w);
        *(short8*)(xL + slot * PT + seg * 16)     = a;
        *(short8*)(xL + slot * PT + seg * 16 + 8) = b;
    }
    __syncthreads();

    const int wv   = t >> 6;
    const int lane = t & 63;
    const int l16  = lane & 15;
    const int quad = lane >> 4;

    f32x4 acc[8][2];
    #pragma unroll
    for (int ml = 0; ml < 8; ++ml)
        #pragma unroll
        for (int nl = 0; nl < 2; ++nl)
            acc[ml][nl] = (f32x4){0.f, 0.f, 0.f, 0.f};

    short8 bf[2][4];
    #pragma unroll
    for (int nl = 0; nl < 2; ++nl)
        #pragma unroll
        for (int ks = 0; ks < 4; ++ks)
            bf[nl][ks] = *(const short8*)(xL + (nl*16 + l16) * PT + ks*32 + quad*8);

    #pragma unroll
    for (int ks = 0; ks < 4; ++ks) {
        short8 af[8];
        #pragma unroll
        for (int ml = 0; ml < 8; ++ml)
            af[ml] = *(const short8*)(WqF + ((size_t)(((wv*8 + ml)*4 + ks)*64 + lane)) * 8);
        #pragma unroll
        for (int ml = 0; ml < 8; ++ml)
            #pragma unroll
            for (int nl = 0; nl < 2; ++nl)
                acc[ml][nl] = __builtin_amdgcn_mfma_f32_16x16x32_bf16(af[ml], bf[nl][ks], acc[ml][nl], 0, 0, 0);
    }

    #pragma unroll
    for (int ml = 0; ml < 8; ++ml) {
        int c0 = wv*128 + ml*16 + quad*4;
        f32x4 bqv = *(const f32x4*)(bq + c0);
        #pragma unroll
        for (int nl = 0; nl < 2; ++nl) {
            int b = b0 + nl*16 + l16;
            short4v hv;
            #pragma unroll
            for (int r = 0; r < 4; ++r) hv[r] = f2bf(acc[ml][nl][r] + bqv[r]);
            *(short4v*)(tokb + (size_t)b * 512 + c0) = hv;
        }
    }
}

// ---------------------------------------------------------------------------
// K1g: gating via collapsed Wkg (scalar K$ loads), softmax/top-2 in registers,
//      FUSED binning into sparse per-expert segments (listIdx[e*NN + pos]),
//      per-block aux partials; last block reduces -> aux loss (out[BB]).
// ---------------------------------------------------------------------------
__global__ __launch_bounds__(256) void k1_gate(
    const float* __restrict__ x, const float* __restrict__ Wkg, const float* __restrict__ bkg,
    float* __restrict__ wts, int* __restrict__ listIdx, int* __restrict__ cursors,
    float* __restrict__ blkPart, int* __restrict__ doneCnt, float* __restrict__ out)
{
    __shared__ float xL[64 * 129];
    __shared__ float lps[EE], lcn[EE];
    __shared__ int   lcnt[EE], lbase[EE];
    __shared__ float red[8][16];
    __shared__ float fin[16];
    __shared__ int   isLast;

    const int t  = threadIdx.x;
    const int b0 = blockIdx.x * 64;

    if (t < EE) { lps[t] = 0.f; lcn[t] = 0.f; lcnt[t] = 0; }

    for (int i = t; i < 2048; i += 256) {
        int r = i >> 5, c = i & 31;
        float4 v = ((const float4*)(x + (size_t)(b0 + r) * 128))[c];
        float* dst = xL + r * 129 + c * 4;
        dst[0] = v.x; dst[1] = v.y; dst[2] = v.z; dst[3] = v.w;
    }
    __syncthreads();

    const int h  = __builtin_amdgcn_readfirstlane(t >> 6);
    const int lb = t & 63;

    const f32x4* wkg4 = (const f32x4*)Wkg;
    f32x4 a0 = ((const f32x4*)bkg)[h * 2];
    f32x4 a1 = ((const f32x4*)bkg)[h * 2 + 1];

    const float* xrow = xL + lb * 129;
    #pragma unroll 4
    for (int k = 0; k < 128; ++k) {
        float xv = xrow[k];
        a0 += wkg4[k * 8 + h * 2]     * xv;
        a1 += wkg4[k * 8 + h * 2 + 1] * xv;
    }

    float l[8] = {a0[0], a0[1], a0[2], a0[3], a1[0], a1[1], a1[2], a1[3]};
    float mx = l[0];
    #pragma unroll
    for (int e = 1; e < 8; ++e) mx = fmaxf(mx, l[e]);
    float p[8]; float sm = 0.f;
    #pragma unroll
    for (int e = 0; e < 8; ++e) { p[e] = __expf(l[e] - mx); sm += p[e]; }
    float isin = 1.f / sm;
    #pragma unroll
    for (int e = 0; e < 8; ++e) p[e] *= isin;

    int i1 = 0; float p1 = p[0];
    #pragma unroll
    for (int e = 1; e < 8; ++e) if (p[e] > p1) { p1 = p[e]; i1 = e; }
    int i2 = (i1 == 0) ? 1 : 0; float p2 = p[i2];
    #pragma unroll
    for (int e = 0; e < 8; ++e) if (e != i1 && p[e] > p2) { p2 = p[e]; i2 = e; }

    const int n = (b0 + lb) * 4 + h;
    float rinv = 1.f / (p1 + p2);
    wts[2*n]   = p1 * rinv;
    wts[2*n+1] = p2 * rinv;

    int s0 = atomicAdd(&lcnt[i1], 1);
    int s1 = atomicAdd(&lcnt[i2], 1);

    #pragma unroll
    for (int e = 0; e < 8; ++e) {
        float v = p[e];
        #pragma unroll
        for (int m2 = 1; m2 < 64; m2 <<= 1) v += __shfl_xor(v, m2);
        unsigned long long m1b = __ballot(i1 == e);
        if (lb == 0) {
            atomicAdd(&lps[e], v);
            atomicAdd(&lcn[e], (float)__popcll(m1b));
        }
    }
    __syncthreads();

    if (t < EE) lbase[t] = atomicAdd(&cursors[t], lcnt[t]);
    if (t < EE) {
        float* bp = blkPart + blockIdx.x * 32;
        bp[t]     = lps[t];
        bp[8 + t] = lcn[t];
    }
    __syncthreads();

    listIdx[i1 * NN + lbase[i1] + s0] = 2 * n;
    listIdx[i2 * NN + lbase[i2] + s1] = 2 * n + 1;

    if (t == 0) {
        __threadfence();
        int prev = atomicAdd(doneCnt, 1);
        isLast = (prev == GNB - 1) ? 1 : 0;
    }
    __syncthreads();
    if (!isLast) return;
    __threadfence();

    if (t < 128) {
        const int chunk = t >> 4, s = t & 15;
        float v = 0.f;
        for (int i = 0; i < 32; ++i) v += blkPart[(chunk * 32 + i) * 32 + s];
        red[chunk][s] = v;
    }
    __syncthreads();
    if (t < 16) {
        float sum = 0.f;
        #pragma unroll
        for (int c = 0; c < 8; ++c) sum += red[c][t];
        fin[t] = sum;
    }
    __syncthreads();
    if (t == 0) {
        float aux = 0.f;
        const float invN = 1.f / (float)NN;
        for (int e = 0; e < EE; ++e)
            aux += (fin[8 + e] * invN) * (fin[e] * invN);
        out[BB] = (float)EE * aux;
    }
}

// ---------------------------------------------------------------------------
// K2b: PERSISTENT expert MLP via bf16 MFMA + fused head.
//   Grid = EE*KPE blocks; block (e, bslot) loops tiles stride KPE.
//   Weight fragments + biases + Wout loaded ONCE per block (registers),
//   reused across tiles: halves the per-tile L2 weight traffic vs R7.
// ---------------------------------------------------------------------------
__global__ __launch_bounds__(256) void k2b_expert(
    const short* __restrict__ tokb, const short* __restrict__ W1F,
    const float* __restrict__ b1, const short* __restrict__ W2F, const float* __restrict__ b2,
    const int* __restrict__ cursors, const int* __restrict__ listIdx,
    const float* __restrict__ wts, const float* __restrict__ Wout, float* __restrict__ out)
{
    __shared__ short tokL[64 * PT];
    __shared__ short hL[64 * PT];
    __shared__ int   ids[64];
    __shared__ float wsl[64];
    __shared__ float WoutL[128];

    const int e     = blockIdx.x >> 7;      // KPE = 128 blocks per expert
    const int bslot = blockIdx.x & (KPE - 1);
    const int cnt   = cursors[e];
    const int ntile = (cnt + 63) >> 6;
    const int t     = threadIdx.x;

    if (t < 128) WoutL[t] = Wout[t];

    const int wv   = t >> 6;
    const int lane = t & 63;
    const int l16  = lane & 15;
    const int quad = lane >> 4;

    // loop-invariant: weight fragments + biases (registers, loaded once)
    short8 af[2][4];
    #pragma unroll
    for (int ml = 0; ml < 2; ++ml)
        #pragma unroll
        for (int ks = 0; ks < 4; ++ks)
            af[ml][ks] = *(const short8*)(W1F + ((size_t)(((e*8 + wv*2 + ml)*4 + ks)*64 + lane)) * 8);

    short8 af2[2][4];
    #pragma unroll
    for (int ml = 0; ml < 2; ++ml)
        #pragma unroll
        for (int ks = 0; ks < 4; ++ks)
            af2[ml][ks] = *(const short8*)(W2F + ((size_t)(((e*2 + ml)*4 + ks)*64 + lane)) * 8);

    f32x4 b1v[2], b2v[2];
    #pragma unroll
    for (int ml = 0; ml < 2; ++ml) {
        b1v[ml] = *(const f32x4*)(b1 + e*128 + wv*32 + ml*16 + quad*4);
        b2v[ml] = *(const f32x4*)(b2 + e*32  + ml*16 + quad*4);
    }

    for (int tile = bslot; tile < ntile; tile += KPE) {
        const int off = tile << 6;
        const int nt  = min(64, cnt - off);
        const int sb  = e * NN + off;

        __syncthreads();   // previous iteration fully consumed LDS
        if (t < 64) {
            int a = listIdx[sb + min(t, nt - 1)];
            ids[t] = a >> 1;
            wsl[t] = (t < nt) ? wts[a] : 0.f;
        }
        __syncthreads();

        #pragma unroll
        for (int r = 0; r < 4; ++r) {
            int i = t + r * 256;
            int slot = i >> 4, seg = i & 15;
            short8 v = *(const short8*)(tokb + (size_t)ids[slot] * 128 + seg * 8);
            *(short8*)(tokL + slot * PT + seg * 8) = v;
        }
        __syncthreads();

        // ---- GEMM1': h[hid][tok], wave owns hid slice [wv*32, wv*32+32) ----
        f32x4 acc[2][4];
        #pragma unroll
        for (int ml = 0; ml < 2; ++ml)
            #pragma unroll
            for (int nl = 0; nl < 4; ++nl)
                acc[ml][nl] = (f32x4){0.f, 0.f, 0.f, 0.f};

        short8 bf[4][4];
        #pragma unroll
        for (int nl = 0; nl < 4; ++nl)
            #pragma unroll
            for (int ks = 0; ks < 4; ++ks)
                bf[nl][ks] = *(const short8*)(tokL + (nl*16 + l16) * PT + ks*32 + quad*8);

        #pragma unroll
        for (int ks = 0; ks < 4; ++ks)
            #pragma unroll
            for (int ml = 0; ml < 2; ++ml)
                #pragma unroll
                for (int nl = 0; nl < 4; ++nl)
                    acc[ml][nl] = __builtin_amdgcn_mfma_f32_16x16x32_bf16(af[ml][ks], bf[nl][ks], acc[ml][nl], 0, 0, 0);

        #pragma unroll
        for (int ml = 0; ml < 2; ++ml) {
            int hid0 = wv*32 + ml*16 + quad*4;
            #pragma unroll
            for (int nl = 0; nl < 4; ++nl) {
                short4v hv;
                #pragma unroll
                for (int r = 0; r < 4; ++r) {
                    float v = acc[ml][nl][r] + b1v[ml][r];
                    hv[r] = f2bf(fmaxf(v, 0.f));
                }
                *(short4v*)(hL + (nl*16 + l16) * PT + hid0) = hv;
            }
        }
        __syncthreads();

        // ---- GEMM2': o[od][tok], wave owns tok tile nl = wv ----
        f32x4 acc2[2];
        acc2[0] = (f32x4){0.f, 0.f, 0.f, 0.f};
        acc2[1] = (f32x4){0.f, 0.f, 0.f, 0.f};

        short8 bf2[4];
        #pragma unroll
        for (int ks = 0; ks < 4; ++ks)
            bf2[ks] = *(const short8*)(hL + (wv*16 + l16) * PT + ks*32 + quad*8);

        #pragma unroll
        for (int ks = 0; ks < 4; ++ks)
            #pragma unroll
            for (int ml = 0; ml < 2; ++ml)
                acc2[ml] = __builtin_amdgcn_mfma_f32_16x16x32_bf16(af2[ml][ks], bf2[ks], acc2[ml], 0, 0, 0);

        // ---- fused head ----
        const int slot = wv*16 + l16;
        const int nn   = ids[slot];
        const int hsel = nn & 3;
        float partial = 0.f;
        #pragma unroll
        for (int ml = 0; ml < 2; ++ml) {
            int od0 = ml*16 + quad*4;
            const float* wseg = WoutL + hsel*32 + od0;
            #pragma unroll
            for (int r = 0; r < 4; ++r)
                partial += (acc2[ml][r] + b2v[ml][r]) * wseg[r];
        }
        partial += __shfl_xor(partial, 16);
        partial += __shfl_xor(partial, 32);
        if (quad == 0) {
            float v = partial * wsl[slot];
            atomicAdd(&out[nn >> 2], v);
        }
    }
}

extern "C" void kernel_launch(void* const* d_in, const int* in_sizes, int n_in,
                              void* d_out, int out_size, void* d_ws, size_t ws_size,
                              hipStream_t stream) {
    (void)in_sizes; (void)n_in; (void)out_size; (void)ws_size;
    const float* x    = (const float*)d_in[0];
    const float* Wq   = (const float*)d_in[1];
    const float* bq   = (const float*)d_in[2];
    const float* Wk   = (const float*)d_in[3];
    const float* bk   = (const float*)d_in[4];
    const float* Wg   = (const float*)d_in[5];
    const float* W1   = (const float*)d_in[6];
    const float* b1   = (const float*)d_in[7];
    const float* W2   = (const float*)d_in[8];
    const float* b2   = (const float*)d_in[9];
    const float* Wout = (const float*)d_in[10];
    const float* bout = (const float*)d_in[11];
    float* out = (float*)d_out;

    char* ws = (char*)d_ws;
    short* tokb     = (short*)(ws + 0);              // 16,777,216
    float* wts      = (float*)(ws + 16777216);       //    524,288
    int*   listIdx  = (int*)  (ws + 17301504);       //  2,097,152 (8 * NN)
    short* WqF      = (short*)(ws + 19398656);       //    131,072
    short* W1F      = (short*)(ws + 19529728);       //    262,144
    short* W2F      = (short*)(ws + 19791872);       //     65,536
    float* Wkg      = (float*)(ws + 19857408);       //     16,384
    float* bkg      = (float*)(ws + 19873792);       //        128
    float* blkPart  = (float*)(ws + 19873920);       //     32,768 (256 blk * 32)
    int*   cursors  = (int*)  (ws + 19906688);       //         32
    int*   doneCnt  = (int*)  (ws + 19906720);       //          4

    prep<<<977, 256, 0, stream>>>(Wq, Wk, Wg, bk, W1, W2, bout,
                                  WqF, W1F, W2F, Wkg, bkg, out, cursors, doneCnt);
    k1q_tok<<<512, 256, 0, stream>>>(x, WqF, bq, tokb);
    k1_gate<<<GNB, 256, 0, stream>>>(x, Wkg, bkg, wts, listIdx, cursors,
                                     blkPart, doneCnt, out);
    k2b_expert<<<EE * KPE, 256, 0, stream>>>(tokb, W1F, b1, W2F, b2,
                                             cursors, listIdx, wts, Wout, out);
}

// Round 9
// 141.307 us; speedup vs baseline: 1.0216x; 1.0216x over previous
//
#include <hip/hip_runtime.h>
#include <hip/hip_bf16.h>

// Problem constants
#define BB   16384
#define DD   128
#define HH   4
#define EE   8
#define NN   (BB*HH)   // 65536
#define OD   32
#define PT   136       // LDS row pitch in bf16 elems (128 + 8)

typedef __attribute__((ext_vector_type(8))) short short8;
typedef __attribute__((ext_vector_type(4))) short short4v;
typedef __attribute__((ext_vector_type(4))) float f32x4;

// RNE float -> bf16 bits
static __device__ __forceinline__ short f2bf(float v) {
    unsigned int u = __builtin_bit_cast(unsigned int, v);
    u = (u + 0x7FFFu + ((u >> 16) & 1u)) >> 16;
    return (short)u;
}

// ---------------------------------------------------------------------------
// PREP (fused): weights -> bf16 in MFMA *fragment order* (coalesced A-loads),
// gate collapse precompute, out[] = bout init.
// Fragment order: for a 16(m)x32(k) A-tile, lane=(quad<<4)|l16 holds
//   m = l16, k = quad*8 + j (j=0..7), stored as 8 contiguous shorts per lane.
//   flat idx = ((tile*4 + ks)*64 + lane)*8 + j,  k = ks*32 + quad*8 + j
// ---------------------------------------------------------------------------
__global__ __launch_bounds__(256) void prep(
    const float* __restrict__ Wq, const float* __restrict__ Wk, const float* __restrict__ Wg,
    const float* __restrict__ bk, const float* __restrict__ W1, const float* __restrict__ W2,
    const float* __restrict__ bout,
    short* __restrict__ WqF, short* __restrict__ W1F, short* __restrict__ W2F,
    float* __restrict__ Wkg, float* __restrict__ bkg, float* __restrict__ out)
{
    int idx = blockIdx.x * 256 + threadIdx.x;
    if (idx < 65536) {
        int j = idx & 7, lane = (idx >> 3) & 63, ks = (idx >> 9) & 3, ct = idx >> 11;
        int l16 = lane & 15, quad = lane >> 4;
        int c = ct * 16 + l16, k = ks * 32 + quad * 8 + j;
        WqF[idx] = f2bf(Wq[k * 512 + c]);
    } else if (idx < 196608) {
        int r = idx - 65536;
        int j = r & 7, lane = (r >> 3) & 63, ks = (r >> 9) & 3, mt = (r >> 11) & 7, e = r >> 14;
        int l16 = lane & 15, quad = lane >> 4;
        int m = mt * 16 + l16, k = ks * 32 + quad * 8 + j;
        W1F[r] = f2bf(W1[e * 16384 + k * 128 + m]);
    } else if (idx < 229376) {
        int r = idx - 196608;
        int j = r & 7, lane = (r >> 3) & 63, ks = (r >> 9) & 3, mt = (r >> 11) & 1, e = r >> 12;
        int l16 = lane & 15, quad = lane >> 4;
        int m = mt * 16 + l16, k = ks * 32 + quad * 8 + j;
        W2F[r] = f2bf(W2[e * 4096 + k * 32 + m]);
    } else if (idx < 233472) {
        int r = idx - 229376;
        int k = r >> 5, col = r & 31, hh = col >> 3, e = col & 7;
        float s = 0.f;
        for (int d = 0; d < 128; ++d) s += Wk[k * 512 + hh * 128 + d] * Wg[d * 8 + e];
        Wkg[k * 32 + col] = s;
    } else if (idx < 233504) {
        int r = idx - 233472;
        int hh = r >> 3, e = r & 7;
        float s = 0.f;
        for (int d = 0; d < 128; ++d) s += bk[hh * 128 + d] * Wg[d * 8 + e];
        bkg[r] = s;
    } else if (idx < 249888) {
        out[idx - 233504] = bout[0];
    }
}

// ---------------------------------------------------------------------------
// K1q: tok = bf16(x @ Wq + bq) via MFMA, D[c][b] (swapped operands).
//      A-frags from fragment-ordered WqF (coalesced 16B/lane loads).
// ---------------------------------------------------------------------------
__global__ __launch_bounds__(256) void k1q_tok(
    const float* __restrict__ x, const short* __restrict__ WqF, const float* __restrict__ bq,
    short* __restrict__ tokb)
{
    __shared__ short xL[32 * PT];
    const int t  = threadIdx.x;
    const int b0 = blockIdx.x * 32;

    {
        int slot = t >> 3, seg = t & 7;
        const float4* src = (const float4*)(x + (size_t)(b0 + slot) * 128 + seg * 16);
        float4 v0 = src[0], v1 = src[1], v2 = src[2], v3 = src[3];
        short8 a, b;
        a[0]=f2bf(v0.x); a[1]=f2bf(v0.y); a[2]=f2bf(v0.z); a[3]=f2bf(v0.w);
        a[4]=f2bf(v1.x); a[5]=f2bf(v1.y); a[6]=f2bf(v1.z); a[7]=f2bf(v1.w);
        b[0]=f2bf(v2.x); b[1]=f2bf(v2.y); b[2]=f2bf(v2.z); b[3]=f2bf(v2.w);
        b[4]=f2bf(v3.x); b[5]=f2bf(v3.y); b[6]=f2bf(v3.z); b[7]=f2bf(v3.w);
        *(short8*)(xL + slot * PT + seg * 16)     = a;
        *(short8*)(xL + slot * PT + seg * 16 + 8) = b;
    }
    __syncthreads();

    const int wv   = t >> 6;
    const int lane = t & 63;
    const int l16  = lane & 15;
    const int quad = lane >> 4;

    f32x4 acc[8][2];
    #pragma unroll
    for (int ml = 0; ml < 8; ++ml)
        #pragma unroll
        for (int nl = 0; nl < 2; ++nl)
            acc[ml][nl] = (f32x4){0.f, 0.f, 0.f, 0.f};

    short8 bf[2][4];
    #pragma unroll
    for (int nl = 0; nl < 2; ++nl)
        #pragma unroll
        for (int ks = 0; ks < 4; ++ks)
            bf[nl][ks] = *(const short8*)(xL + (nl*16 + l16) * PT + ks*32 + quad*8);

    #pragma unroll
    for (int ks = 0; ks < 4; ++ks) {
        short8 af[8];
        #pragma unroll
        for (int ml = 0; ml < 8; ++ml)
            af[ml] = *(const short8*)(WqF + ((size_t)(((wv*8 + ml)*4 + ks)*64 + lane)) * 8);
        #pragma unroll
        for (int ml = 0; ml < 8; ++ml)
            #pragma unroll
            for (int nl = 0; nl < 2; ++nl)
                acc[ml][nl] = __builtin_amdgcn_mfma_f32_16x16x32_bf16(af[ml], bf[nl][ks], acc[ml][nl], 0, 0, 0);
    }

    #pragma unroll
    for (int ml = 0; ml < 8; ++ml) {
        int c0 = wv*128 + ml*16 + quad*4;
        f32x4 bqv = *(const f32x4*)(bq + c0);
        #pragma unroll
        for (int nl = 0; nl < 2; ++nl) {
            int b = b0 + nl*16 + l16;
            short4v hv;
            #pragma unroll
            for (int r = 0; r < 4; ++r) hv[r] = f2bf(acc[ml][nl][r] + bqv[r]);
            *(short4v*)(tokb + (size_t)b * 512 + c0) = hv;
        }
    }
}

// ---------------------------------------------------------------------------
// K1g: gating via collapsed Wkg (scalar K$ loads), softmax/top-2 in registers,
//      per-block partials (no global atomics).
// ---------------------------------------------------------------------------
__global__ __launch_bounds__(256) void k1_gate(
    const float* __restrict__ x, const float* __restrict__ Wkg, const float* __restrict__ bkg,
    int* __restrict__ topi, float* __restrict__ wts, float* __restrict__ blkPart)
{
    __shared__ float xL[64 * 129];
    __shared__ float lps[EE];
    __shared__ float lcn[EE];
    __shared__ float lasg[EE];

    const int t  = threadIdx.x;
    const int b0 = blockIdx.x * 64;

    if (t < EE) { lps[t] = 0.f; lcn[t] = 0.f; lasg[t] = 0.f; }

    for (int i = t; i < 2048; i += 256) {
        int r = i >> 5, c = i & 31;
        float4 v = ((const float4*)(x + (size_t)(b0 + r) * 128))[c];
        float* dst = xL + r * 129 + c * 4;
        dst[0] = v.x; dst[1] = v.y; dst[2] = v.z; dst[3] = v.w;
    }
    __syncthreads();

    const int h  = __builtin_amdgcn_readfirstlane(t >> 6);
    const int lb = t & 63;

    const f32x4* wkg4 = (const f32x4*)Wkg;
    f32x4 a0 = ((const f32x4*)bkg)[h * 2];
    f32x4 a1 = ((const f32x4*)bkg)[h * 2 + 1];

    const float* xrow = xL + lb * 129;
    #pragma unroll 4
    for (int k = 0; k < 128; ++k) {
        float xv = xrow[k];
        a0 += wkg4[k * 8 + h * 2]     * xv;
        a1 += wkg4[k * 8 + h * 2 + 1] * xv;
    }

    float l[8] = {a0[0], a0[1], a0[2], a0[3], a1[0], a1[1], a1[2], a1[3]};
    float mx = l[0];
    #pragma unroll
    for (int e = 1; e < 8; ++e) mx = fmaxf(mx, l[e]);
    float p[8]; float sm = 0.f;
    #pragma unroll
    for (int e = 0; e < 8; ++e) { p[e] = __expf(l[e] - mx); sm += p[e]; }
    float isin = 1.f / sm;
    #pragma unroll
    for (int e = 0; e < 8; ++e) p[e] *= isin;

    int i1 = 0; float p1 = p[0];
    #pragma unroll
    for (int e = 1; e < 8; ++e) if (p[e] > p1) { p1 = p[e]; i1 = e; }
    int i2 = (i1 == 0) ? 1 : 0; float p2 = p[i2];
    #pragma unroll
    for (int e = 0; e < 8; ++e) if (e != i1 && p[e] > p2) { p2 = p[e]; i2 = e; }

    int n = (b0 + lb) * 4 + h;
    float rinv = 1.f / (p1 + p2);
    topi[2*n]   = i1;        topi[2*n+1] = i2;
    wts[2*n]    = p1 * rinv; wts[2*n+1]  = p2 * rinv;

    #pragma unroll
    for (int e = 0; e < 8; ++e) {
        float v = p[e];
        #pragma unroll
        for (int m2 = 1; m2 < 64; m2 <<= 1) v += __shfl_xor(v, m2);
        unsigned long long m1b = __ballot(i1 == e);
        unsigned long long m2b = __ballot(i2 == e);
        if (lb == 0) {
            float c1 = (float)__popcll(m1b);
            atomicAdd(&lps[e], v);
            atomicAdd(&lcn[e], c1);
            atomicAdd(&lasg[e], c1 + (float)__popcll(m2b));
        }
    }
    __syncthreads();
    if (t < EE) {
        float* bp = blkPart + blockIdx.x * 32;
        bp[t]      = lps[t];
        bp[8 + t]  = lcn[t];
        bp[16 + t] = lasg[t];
    }
}

// ---------------------------------------------------------------------------
// K2s: reduce partials -> aux loss (out[BB]), 64-padded bases + cursors.
// ---------------------------------------------------------------------------
__global__ __launch_bounds__(256) void k2s_scan(
    const float* __restrict__ blkPart,
    int* __restrict__ bases, int* __restrict__ cursors, int* __restrict__ assignCnt,
    float* __restrict__ out)
{
    __shared__ float red[8][32];
    __shared__ float fin[24];
    const int t = threadIdx.x;
    const int chunk = t >> 5, s = t & 31;
    float v = 0.f;
    for (int i = 0; i < 32; ++i) v += blkPart[(chunk * 32 + i) * 32 + s];
    red[chunk][s] = v;
    __syncthreads();
    if (t < 24) {
        float sum = 0.f;
        #pragma unroll
        for (int c = 0; c < 8; ++c) sum += red[c][t];
        fin[t] = sum;
    }
    __syncthreads();
    if (t == 0) {
        int b = 0;
        float aux = 0.f;
        const float invN = 1.f / (float)NN;
        for (int e = 0; e < EE; ++e) {
            aux += (fin[8 + e] * invN) * (fin[e] * invN);
            int a = (int)(fin[16 + e] + 0.5f);
            assignCnt[e] = a;
            bases[e] = b; cursors[e] = b;
            b += (a + 63) & ~63;
        }
        out[BB] = (float)EE * aux;
    }
}

// ---------------------------------------------------------------------------
// K2a: bin assignments into compact per-expert lists; value = 2*n + rank
// ---------------------------------------------------------------------------
__global__ __launch_bounds__(256) void k2a_bin(
    const int* __restrict__ topi,
    int* __restrict__ cursors, int* __restrict__ listIdx)
{
    __shared__ int lcnt[EE];
    __shared__ int lbase[EE];
    int t = threadIdx.x;
    if (t < EE) lcnt[t] = 0;
    __syncthreads();
    int n = blockIdx.x * 256 + t;
    int i0 = topi[2*n], i1 = topi[2*n+1];
    int s0 = atomicAdd(&lcnt[i0], 1);
    int s1 = atomicAdd(&lcnt[i1], 1);
    __syncthreads();
    if (t < EE) lbase[t] = atomicAdd(&cursors[t], lcnt[t]);
    __syncthreads();
    listIdx[lbase[i0] + s0] = 2*n;
    listIdx[lbase[i1] + s1] = 2*n + 1;
}

// ---------------------------------------------------------------------------
// K2b: expert MLP via bf16 MFMA + fused head. 64 tokens of one expert/block.
//   GEMM1': h[hid][tok] = W1F . tok^T  (128x64x128) relu+bias -> hL
//   GEMM2': o[od][tok]  = W2F . h^T    (32x64x128)  +bias
//   head:   out[n>>2] += w * dot(o, Wout[h*32..h*32+32))   (atomic, 64/block)
// ---------------------------------------------------------------------------
__global__ __launch_bounds__(256) void k2b_expert(
    const short* __restrict__ tokb, const short* __restrict__ W1F,
    const float* __restrict__ b1, const short* __restrict__ W2F, const float* __restrict__ b2,
    const int* __restrict__ assignCnt, const int* __restrict__ bases,
    const int* __restrict__ listIdx, const float* __restrict__ wts,
    const float* __restrict__ Wout, float* __restrict__ out)
{
    __shared__ short tokL[64 * PT];
    __shared__ short hL[64 * PT];
    __shared__ int   ids[64];
    __shared__ float wsl[64];
    __shared__ float WoutL[128];

    const int e    = blockIdx.y;
    const int cnt  = assignCnt[e];
    const int off  = blockIdx.x * 64;
    if (off >= cnt) return;
    const int sb   = bases[e] + off;
    const int t    = threadIdx.x;
    const int nt   = min(64, cnt - off);

    if (t < 64) {
        int a = listIdx[sb + min(t, nt - 1)];
        ids[t] = a >> 1;
        wsl[t] = (t < nt) ? wts[a] : 0.f;
    }
    if (t >= 128 && t < 256) WoutL[t - 128] = Wout[t - 128];
    __syncthreads();

    #pragma unroll
    for (int r = 0; r < 4; ++r) {
        int i = t + r * 256;
        int slot = i >> 4, seg = i & 15;
        short8 v = *(const short8*)(tokb + (size_t)ids[slot] * 128 + seg * 8);
        *(short8*)(tokL + slot * PT + seg * 8) = v;
    }
    __syncthreads();

    const int wv   = t >> 6;
    const int lane = t & 63;
    const int l16  = lane & 15;
    const int quad = lane >> 4;

    // ---- GEMM1': wave owns hid slice [wv*32, wv*32+32) ----
    f32x4 acc[2][4];
    #pragma unroll
    for (int ml = 0; ml < 2; ++ml)
        #pragma unroll
        for (int nl = 0; nl < 4; ++nl)
            acc[ml][nl] = (f32x4){0.f, 0.f, 0.f, 0.f};

    short8 af[2][4];
    #pragma unroll
    for (int ml = 0; ml < 2; ++ml)
        #pragma unroll
        for (int ks = 0; ks < 4; ++ks)
            af[ml][ks] = *(const short8*)(W1F + ((size_t)(((e*8 + wv*2 + ml)*4 + ks)*64 + lane)) * 8);

    short8 bf[4][4];
    #pragma unroll
    for (int nl = 0; nl < 4; ++nl)
        #pragma unroll
        for (int ks = 0; ks < 4; ++ks)
            bf[nl][ks] = *(const short8*)(tokL + (nl*16 + l16) * PT + ks*32 + quad*8);

    #pragma unroll
    for (int ks = 0; ks < 4; ++ks)
        #pragma unroll
        for (int ml = 0; ml < 2; ++ml)
            #pragma unroll
            for (int nl = 0; nl < 4; ++nl)
                acc[ml][nl] = __builtin_amdgcn_mfma_f32_16x16x32_bf16(af[ml][ks], bf[nl][ks], acc[ml][nl], 0, 0, 0);

    #pragma unroll
    for (int ml = 0; ml < 2; ++ml) {
        int hid0 = wv*32 + ml*16 + quad*4;
        f32x4 b1v = *(const f32x4*)(b1 + e*128 + hid0);
        #pragma unroll
        for (int nl = 0; nl < 4; ++nl) {
            short4v hv;
            #pragma unroll
            for (int r = 0; r < 4; ++r) {
                float v = acc[ml][nl][r] + b1v[r];
                hv[r] = f2bf(fmaxf(v, 0.f));
            }
            *(short4v*)(hL + (nl*16 + l16) * PT + hid0) = hv;
        }
    }
    __syncthreads();

    // ---- GEMM2': wave owns tok tile nl = wv ----
    f32x4 acc2[2];
    acc2[0] = (f32x4){0.f, 0.f, 0.f, 0.f};
    acc2[1] = (f32x4){0.f, 0.f, 0.f, 0.f};

    short8 af2[2][4];
    #pragma unroll
    for (int ml = 0; ml < 2; ++ml)
        #pragma unroll
        for (int ks = 0; ks < 4; ++ks)
            af2[ml][ks] = *(const short8*)(W2F + ((size_t)(((e*2 + ml)*4 + ks)*64 + lane)) * 8);

    short8 bf2[4];
    #pragma unroll
    for (int ks = 0; ks < 4; ++ks)
        bf2[ks] = *(const short8*)(hL + (wv*16 + l16) * PT + ks*32 + quad*8);

    #pragma unroll
    for (int ks = 0; ks < 4; ++ks)
        #pragma unroll
        for (int ml = 0; ml < 2; ++ml)
            acc2[ml] = __builtin_amdgcn_mfma_f32_16x16x32_bf16(af2[ml][ks], bf2[ks], acc2[ml], 0, 0, 0);

    // ---- fused head ----
    const int slot = wv*16 + l16;
    const int nn   = ids[slot];
    const int hsel = nn & 3;
    float partial = 0.f;
    #pragma unroll
    for (int ml = 0; ml < 2; ++ml) {
        int od0 = ml*16 + quad*4;
        f32x4 b2v = *(const f32x4*)(b2 + e*32 + od0);
        const float* wseg = WoutL + hsel*32 + od0;
        #pragma unroll
        for (int r = 0; r < 4; ++r)
            partial += (acc2[ml][r] + b2v[r]) * wseg[r];
    }
    partial += __shfl_xor(partial, 16);
    partial += __shfl_xor(partial, 32);
    if (quad == 0) {
        float v = partial * wsl[slot];
        atomicAdd(&out[nn >> 2], v);
    }
}

extern "C" void kernel_launch(void* const* d_in, const int* in_sizes, int n_in,
                              void* d_out, int out_size, void* d_ws, size_t ws_size,
                              hipStream_t stream) {
    (void)in_sizes; (void)n_in; (void)out_size; (void)ws_size;
    const float* x    = (const float*)d_in[0];
    const float* Wq   = (const float*)d_in[1];
    const float* bq   = (const float*)d_in[2];
    const float* Wk   = (const float*)d_in[3];
    const float* bk   = (const float*)d_in[4];
    const float* Wg   = (const float*)d_in[5];
    const float* W1   = (const float*)d_in[6];
    const float* b1   = (const float*)d_in[7];
    const float* W2   = (const float*)d_in[8];
    const float* b2   = (const float*)d_in[9];
    const float* Wout = (const float*)d_in[10];
    const float* bout = (const float*)d_in[11];
    float* out = (float*)d_out;

    char* ws = (char*)d_ws;
    short* tokb     = (short*)(ws + 0);              // 16,777,216
    int*   topi     = (int*)  (ws + 16777216);       //    524,288
    float* wts      = (float*)(ws + 17301504);       //    524,288
    int*   listIdx  = (int*)  (ws + 17825792);       //    526,336
    short* WqF      = (short*)(ws + 18352128);       //    131,072
    short* W1F      = (short*)(ws + 18483200);       //    262,144
    short* W2F      = (short*)(ws + 18745344);       //     65,536
    float* Wkg      = (float*)(ws + 18810880);       //     16,384
    float* bkg      = (float*)(ws + 18827264);       //        128
    float* blkPart  = (float*)(ws + 18827392);       //     32,768
    int*   bases    = (int*)  (ws + 18860160);       //         32
    int*   cursors  = (int*)  (ws + 18860192);       //         32
    int*   assignCnt= (int*)  (ws + 18860224);       //         32

    prep<<<977, 256, 0, stream>>>(Wq, Wk, Wg, bk, W1, W2, bout, WqF, W1F, W2F, Wkg, bkg, out);
    k1q_tok<<<512, 256, 0, stream>>>(x, WqF, bq, tokb);
    k1_gate<<<256, 256, 0, stream>>>(x, Wkg, bkg, topi, wts, blkPart);
    k2s_scan<<<1, 256, 0, stream>>>(blkPart, bases, cursors, assignCnt, out);
    k2a_bin<<<256, 256, 0, stream>>>(topi, cursors, listIdx);
    k2b_expert<<<dim3(1024, 8), 256, 0, stream>>>(tokb, W1F, b1, W2F, b2, assignCnt, bases,
                                                  listIdx, wts, Wout, out);
}